// Round 12
// baseline (112.451 us; speedup 1.0000x reference)
//
#include <hip/hip_runtime.h>
#include <math.h>

// ---- problem constants ----
#define NCH   8
#define IMN   256
#define OSN   320
#define NPTS  (64*4096)            // 262144 trajectory points
#define KD    512                  // doubled K (re,im interleaved)
#define BETA_F   10.9551078f
#define BETA2_F  120.014389f
#define APOD_C   0.05890486225f    // pi*6/320
// padded halo grid: phys row/col = logical + 3; rows 0-2 = logical 317-319,
// rows 323-325 = logical 0-2 (same for cols). Row pitch 328 cols.
#define GROWS 326
#define GCOLS 328
#define GPITCH (GCOLS * NCH)       // u32 per padded grid row = 2624

typedef unsigned short u16;
typedef unsigned int   u32;
typedef __attribute__((ext_vector_type(8))) short s16x8;   // 8 bf16 (4 VGPRs)
typedef __attribute__((ext_vector_type(4))) float f32x4;   // MFMA acc
typedef __attribute__((ext_vector_type(2))) float f32x2;   // packed re,im

__device__ __forceinline__ u32 f2bf(float f) {
    u32 u = __float_as_uint(f);
    return (u + 0x7FFFu + ((u >> 16) & 1u)) >> 16;
}

// B2 = interleave(im, re) derived from B1 = interleave(re, -im):
// per dword: rot16 then flip sign of the (new) low half. Bit-identical to
// a stored table since f2bf(-x) == f2bf(x)^0x8000.
__device__ __forceinline__ s16x8 derive_b2(s16x8 b) {
    union { s16x8 v; u32 d[4]; } in, out;
    in.v = b;
    #pragma unroll
    for (int i = 0; i < 4; i++) {
        u32 v = in.d[i];
        out.d[i] = ((v >> 16) | (v << 16)) ^ 0x8000u;
    }
    return out.v;
}

// Kaiser-Bessel i0 (A&S), rel err ~5e-7
__device__ __forceinline__ float i0f(float t) {
    if (t < 3.75f) {
        float y = t * t * (1.0f / 14.0625f);
        return 1.0f + y * (3.5156229f + y * (3.0899424f + y * (1.2067492f +
                     y * (0.2659732f + y * (0.0360768f + y * 0.0045813f)))));
    }
    float z = 3.75f / t;
    float p = 0.39894228f + z * (0.01328592f + z * (0.00225319f + z * (-0.00157565f +
              z * (0.00916281f + z * (-0.02057706f + z * (0.02635537f +
              z * (-0.01647633f + z * 0.00392377f)))))));
    return expf(t) * rsqrtf(t) * p;
}

__device__ __forceinline__ float apodf(int i) {
    float x = APOD_C * (float)(i - IMN / 2);
    float arg = sqrtf(BETA2_F - x * x);
    float e = expf(arg);
    float sh = 0.5f * (e - 1.0f / e);
    return arg / sh;
}

// Merged prep: blocks [0,320) build B1 only (B2 derived in the GEMMs);
// blocks [320, 2368) build Abf.
// B1[k][kd] = interleave(M2re, -M2im)
// Abf[c][i1][kd]: apodized complex image, bf16, (re,im) interleaved along kd
__global__ void prep(const float* __restrict__ r, const float* __restrict__ im,
                     u32* __restrict__ B1, u32* __restrict__ A) {
    const int b = blockIdx.x, t = threadIdx.x;
    if (b < (OSN * IMN) / 256) {
        int idx = b * 256 + t;
        int k = idx >> 8, j = idx & 255;
        int p = (k * (j + 32)) % OSN;
        float th = (2.0f * (float)M_PI / (float)OSN) * (float)p;
        float s = ((k + j) & 1) ? -1.0f : 1.0f;
        float sn, cs;
        sincosf(th, &sn, &cs);
        float re = s * cs, imv = -s * sn;
        B1[idx] = f2bf(re) | (f2bf(-imv) << 16);
    } else {
        int idx = (b - (OSN * IMN) / 256) * 256 + t;
        int i2 = idx & 255, i1 = (idx >> 8) & 255;
        float w = apodf(i1) * apodf(i2) * (1.0f / 256.0f);
        A[idx] = f2bf(r[idx] * w) | (f2bf(im[idx] * w) << 16);
    }
}

// GEMM1 (MFMA): Tb[c][k2][kd], kd=2*i1(re),2*i1+1(im).
// R24 config (measured best): NO LDS, 32x32 per-wave tile, 4 loads +
// 2 derives + 8 MFMA per K-step, zero barriers. Grid (10,8,8)=640 waves.
__launch_bounds__(64)
__global__ void gemm1(const short* __restrict__ Abf, const short* __restrict__ B1,
                      short* __restrict__ Tb) {
    const int c = blockIdx.z;
    const int mBase = blockIdx.y * 32;   // i1
    const int nBase = blockIdx.x * 32;   // k2
    const int t = threadIdx.x;
    const int fm = t & 15, fq = (t >> 4) * 8;
    const short* pa0  = Abf + (long)(c * IMN + mBase + fm) * KD + fq;
    const short* pa1  = pa0 + 16 * KD;
    const short* pb10 = B1 + (long)(nBase + fm) * KD + fq;
    const short* pb11 = pb10 + 16 * KD;
    f32x4 zz = {0.f, 0.f, 0.f, 0.f};
    f32x4 accRe[2][2], accIm[2][2];
    #pragma unroll
    for (int i = 0; i < 2; i++)
        #pragma unroll
        for (int j = 0; j < 2; j++) { accRe[i][j] = zz; accIm[i][j] = zz; }

    #pragma unroll
    for (int kc = 0; kc < 16; kc++) {
        const int kb = kc * 32;
        s16x8 a0  = *(const s16x8*)(pa0  + kb);
        s16x8 a1  = *(const s16x8*)(pa1  + kb);
        s16x8 b10 = *(const s16x8*)(pb10 + kb);
        s16x8 b11 = *(const s16x8*)(pb11 + kb);
        s16x8 b20 = derive_b2(b10);
        s16x8 b21 = derive_b2(b11);
        accRe[0][0] = __builtin_amdgcn_mfma_f32_16x16x32_bf16(a0, b10, accRe[0][0], 0, 0, 0);
        accRe[0][1] = __builtin_amdgcn_mfma_f32_16x16x32_bf16(a0, b11, accRe[0][1], 0, 0, 0);
        accRe[1][0] = __builtin_amdgcn_mfma_f32_16x16x32_bf16(a1, b10, accRe[1][0], 0, 0, 0);
        accRe[1][1] = __builtin_amdgcn_mfma_f32_16x16x32_bf16(a1, b11, accRe[1][1], 0, 0, 0);
        accIm[0][0] = __builtin_amdgcn_mfma_f32_16x16x32_bf16(a0, b20, accIm[0][0], 0, 0, 0);
        accIm[0][1] = __builtin_amdgcn_mfma_f32_16x16x32_bf16(a0, b21, accIm[0][1], 0, 0, 0);
        accIm[1][0] = __builtin_amdgcn_mfma_f32_16x16x32_bf16(a1, b20, accIm[1][0], 0, 0, 0);
        accIm[1][1] = __builtin_amdgcn_mfma_f32_16x16x32_bf16(a1, b21, accIm[1][1], 0, 0, 0);
    }
    // C/D layout: col = lane&15, row = (lane>>4)*4 + reg
    #pragma unroll
    for (int i = 0; i < 2; i++)
        #pragma unroll
        for (int j = 0; j < 2; j++) {
            int i1b = mBase + i * 16 + (t >> 4) * 4;
            int k2  = nBase + j * 16 + fm;
            s16x8 v;
            #pragma unroll
            for (int r = 0; r < 4; r++) {
                v[2 * r]     = (short)f2bf(accRe[i][j][r]);
                v[2 * r + 1] = (short)f2bf(accIm[i][j][r]);
            }
            *(s16x8*)(Tb + ((long)(c * OSN + k2)) * KD + 2 * i1b) = v;
        }
}

// GEMM2 (MFMA): Gb = padded halo grid [326][328][8] packed bf16.
// R24 config: NO LDS, 32x32 tile, 4 loads/K-step (a2 derived from a1).
// Border elements replicated into the halo (up to 4 stores).
__launch_bounds__(64)
__global__ void gemm2(const short* __restrict__ B1, const short* __restrict__ Tb,
                      u32* __restrict__ Gb) {
    const int c = blockIdx.z;
    const int mBase = blockIdx.y * 32;   // k1
    const int nBase = blockIdx.x * 32;   // k2
    const int t = threadIdx.x;
    const int fm = t & 15, fq = (t >> 4) * 8;
    const short* pa10 = B1 + (long)(mBase + fm) * KD + fq;
    const short* pa11 = pa10 + 16 * KD;
    const short* pb0  = Tb + ((long)(c * OSN + nBase + fm)) * KD + fq;
    const short* pb1  = pb0 + 16 * KD;
    f32x4 zz = {0.f, 0.f, 0.f, 0.f};
    f32x4 accRe[2][2], accIm[2][2];
    #pragma unroll
    for (int i = 0; i < 2; i++)
        #pragma unroll
        for (int j = 0; j < 2; j++) { accRe[i][j] = zz; accIm[i][j] = zz; }

    #pragma unroll
    for (int kc = 0; kc < 16; kc++) {
        const int kb = kc * 32;
        s16x8 a10 = *(const s16x8*)(pa10 + kb);
        s16x8 a11 = *(const s16x8*)(pa11 + kb);
        s16x8 b0  = *(const s16x8*)(pb0  + kb);
        s16x8 b1  = *(const s16x8*)(pb1  + kb);
        s16x8 a20 = derive_b2(a10);
        s16x8 a21 = derive_b2(a11);
        accRe[0][0] = __builtin_amdgcn_mfma_f32_16x16x32_bf16(a10, b0, accRe[0][0], 0, 0, 0);
        accRe[0][1] = __builtin_amdgcn_mfma_f32_16x16x32_bf16(a10, b1, accRe[0][1], 0, 0, 0);
        accRe[1][0] = __builtin_amdgcn_mfma_f32_16x16x32_bf16(a11, b0, accRe[1][0], 0, 0, 0);
        accRe[1][1] = __builtin_amdgcn_mfma_f32_16x16x32_bf16(a11, b1, accRe[1][1], 0, 0, 0);
        accIm[0][0] = __builtin_amdgcn_mfma_f32_16x16x32_bf16(a20, b0, accIm[0][0], 0, 0, 0);
        accIm[0][1] = __builtin_amdgcn_mfma_f32_16x16x32_bf16(a20, b1, accIm[0][1], 0, 0, 0);
        accIm[1][0] = __builtin_amdgcn_mfma_f32_16x16x32_bf16(a21, b0, accIm[1][0], 0, 0, 0);
        accIm[1][1] = __builtin_amdgcn_mfma_f32_16x16x32_bf16(a21, b1, accIm[1][1], 0, 0, 0);
    }
    #pragma unroll
    for (int i = 0; i < 2; i++)
        #pragma unroll
        for (int j = 0; j < 2; j++) {
            int k2 = nBase + j * 16 + fm;
            int pc  = k2 + 3;
            int pc2 = (k2 < 3) ? (k2 + 323) : ((k2 >= 317) ? (k2 - 317) : -1);
            #pragma unroll
            for (int r = 0; r < 4; r++) {
                int k1 = mBase + i * 16 + (t >> 4) * 4 + r;
                u32 val = f2bf(accRe[i][j][r]) | (f2bf(accIm[i][j][r]) << 16);
                int pr  = k1 + 3;
                int pr2 = (k1 < 3) ? (k1 + 323) : ((k1 >= 317) ? (k1 - 317) : -1);
                Gb[(long)pr * GPITCH + pc * NCH + c] = val;
                if (pr2 >= 0)              Gb[(long)pr2 * GPITCH + pc  * NCH + c] = val;
                if (pc2 >= 0)              Gb[(long)pr  * GPITCH + pc2 * NCH + c] = val;
                if (pr2 >= 0 && pc2 >= 0)  Gb[(long)pr2 * GPITCH + pc2 * NCH + c] = val;
            }
        }
}

// KB interpolation — padded halo grid, no wrap/modulo.
// R28: 128 pts/block, 2 lanes/point x 4 channels (uint4) — halves wave-level
// load-instruction count vs R27 at identical 32B-segment count and identical
// in-flight bytes/CU. All 36 uint4 issued up front (144 VGPR;
// __launch_bounds__(256,2) allows 256). 4-channel f32x2 accumulate in
// dx-outer/dy-inner order = R20/R21 scheme (measured bit-identical).
__launch_bounds__(256, 2)
__global__ void interp_kernel(const float* __restrict__ trj,
                              const u32* __restrict__ grid,
                              u32* __restrict__ out) {
    const int t = threadIdx.x;
    __shared__ float wxs[128][6], wys[128][6];
    __shared__ int   x0s[128], y0s[128];

    // 1536 weight evals / 256 threads = 6 each: thread t handles
    // axis (t>>7) of point (t&127).
    {
        int ptl = t & 127, axis = t >> 7;
        int pt = blockIdx.x * 128 + ptl;
        float tv = trj[pt * 2 + axis];
        float cc = __fadd_rn(__fmul_rn(tv, 1.25f), 160.0f);
        float v0 = ceilf(__fadd_rn(cc, -3.0f));
        if (axis) y0s[ptl] = (int)v0; else x0s[ptl] = (int)v0;
        float* ws = axis ? wys[ptl] : wxs[ptl];
        #pragma unroll
        for (int d = 0; d < 6; d++) {
            float u = __fdiv_rn(__fsub_rn(v0 + (float)d, cc), 3.0f);
            ws[d] = i0f(BETA_F * sqrtf(fmaxf(1.0f - u * u, 0.0f)));
        }
    }
    __syncthreads();

    const int pl  = t >> 1;                // point 0..127
    const int cp4 = (t & 1) * 4;           // channel quad base (0 or 4)
    const int px = x0s[pl] + 3;            // phys row start, in [0,320]
    const int py = y0s[pl] + 3;            // phys col start, in [0,320]
    const u32* g0 = grid + (long)px * GPITCH + py * NCH + cp4;

    // issue all 36 loads before any use (compile-time indices -> registers)
    uint4 g[36];
    #pragma unroll
    for (int dx = 0; dx < 6; dx++)
        #pragma unroll
        for (int dy = 0; dy < 6; dy++)
            g[dx * 6 + dy] = *(const uint4*)(g0 + dx * GPITCH + dy * NCH);

    float wx[6], wy[6];
    #pragma unroll
    for (int d = 0; d < 6; d++) { wx[d] = wxs[pl][d]; wy[d] = wys[pl][d]; }

    f32x2 a0 = {0.f, 0.f}, a1 = {0.f, 0.f}, a2 = {0.f, 0.f}, a3 = {0.f, 0.f};
    #pragma unroll
    for (int dx = 0; dx < 6; dx++) {
        float wxv = wx[dx];
        #pragma unroll
        for (int dy = 0; dy < 6; dy++) {
            uint4 gv = g[dx * 6 + dy];
            float ww = wxv * wy[dy];
            f32x2 w2 = {ww, ww};
            f32x2 v0v = { __uint_as_float(gv.x << 16), __uint_as_float(gv.x & 0xFFFF0000u) };
            f32x2 v1v = { __uint_as_float(gv.y << 16), __uint_as_float(gv.y & 0xFFFF0000u) };
            f32x2 v2v = { __uint_as_float(gv.z << 16), __uint_as_float(gv.z & 0xFFFF0000u) };
            f32x2 v3v = { __uint_as_float(gv.w << 16), __uint_as_float(gv.w & 0xFFFF0000u) };
            a0 += v0v * w2;
            a1 += v1v * w2;
            a2 += v2v * w2;
            a3 += v3v * w2;
        }
    }
    f32x2 sc = {1.0f / 36.0f, 1.0f / 36.0f};
    a0 *= sc; a1 *= sc; a2 *= sc; a3 *= sc;

    __shared__ float2 lds[128][9];         // [point][channel], +1 pad
    lds[pl][cp4]     = make_float2(a0.x, a0.y);
    lds[pl][cp4 + 1] = make_float2(a1.x, a1.y);
    lds[pl][cp4 + 2] = make_float2(a2.x, a2.y);
    lds[pl][cp4 + 3] = make_float2(a3.x, a3.y);
    __syncthreads();
    // writes: 8 ch x 128 pts = 1024 u32; thread writes 4 pts of ch c2
    int c2 = t >> 5, p2 = t & 31;
    long ob = (long)c2 * NPTS + blockIdx.x * 128;
    #pragma unroll
    for (int k = 0; k < 4; k++) {
        float2 v = lds[p2 + 32 * k][c2];
        out[ob + p2 + 32 * k] = f2bf(v.y) | (f2bf(v.x) << 16);   // (imag, real)
    }
}

extern "C" void kernel_launch(void* const* d_in, const int* in_sizes, int n_in,
                              void* d_out, int out_size, void* d_ws, size_t ws_size,
                              hipStream_t stream) {
    const float* img_r = (const float*)d_in[0];
    const float* img_i = (const float*)d_in[1];
    const float* trj   = (const float*)d_in[2];

    // d_out (8,388,608 B) scratch (dead before interp overwrites):
    //   Tb @ 0 : 2,621,440 B   B1 @ 2,621,440 : 327,680 B
    //   Abf @ 3,276,800 : 2,097,152 B   (B2 eliminated — derived in-register)
    // d_ws: Gb padded halo grid [326][328][8] u32 = 3,421,696 B.
    char* ob = (char*)d_out;
    short* Tb  = (short*)(ob);
    u32*  B1u  = (u32*)(ob + 2621440);
    u32*  Au   = (u32*)(ob + 3276800);
    u32*  Gb   = (u32*)d_ws;

    prep<<<(OSN * IMN) / 256 + (NCH * IMN * IMN) / 256, 256, 0, stream>>>(
        img_r, img_i, B1u, Au);
    gemm1<<<dim3(OSN / 32, IMN / 32, NCH), 64, 0, stream>>>(
        (const short*)Au, (const short*)B1u, Tb);
    gemm2<<<dim3(OSN / 32, OSN / 32, NCH), 64, 0, stream>>>(
        (const short*)B1u, Tb, Gb);
    interp_kernel<<<NPTS / 128, 256, 0, stream>>>(trj, Gb, (u32*)d_out);
}

// Round 13
// 110.474 us; speedup vs baseline: 1.0179x; 1.0179x over previous
//
#include <hip/hip_runtime.h>
#include <math.h>

// ---- problem constants ----
#define NCH   8
#define IMN   256
#define OSN   320
#define NPTS  (64*4096)            // 262144 trajectory points
#define KD    512                  // doubled K (re,im interleaved)
#define BETA_F   10.9551078f
#define BETA2_F  120.014389f
#define APOD_C   0.05890486225f    // pi*6/320
// padded halo grid: phys row/col = logical + 3; rows 0-2 = logical 317-319,
// rows 323-325 = logical 0-2 (same for cols). Row pitch 328 cols.
#define GROWS 326
#define GCOLS 328
#define GPITCH (GCOLS * NCH)       // u32 per padded grid row = 2624

typedef unsigned short u16;
typedef unsigned int   u32;
typedef __attribute__((ext_vector_type(8))) short s16x8;   // 8 bf16 (4 VGPRs)
typedef __attribute__((ext_vector_type(4))) float f32x4;   // MFMA acc
typedef __attribute__((ext_vector_type(2))) float f32x2;   // packed re,im

__device__ __forceinline__ u32 f2bf(float f) {
    u32 u = __float_as_uint(f);
    return (u + 0x7FFFu + ((u >> 16) & 1u)) >> 16;
}

// B2 = interleave(im, re) derived from B1 = interleave(re, -im):
// per dword: rot16 then flip sign of the (new) low half. Bit-identical to
// a stored table since f2bf(-x) == f2bf(x)^0x8000.
__device__ __forceinline__ s16x8 derive_b2(s16x8 b) {
    union { s16x8 v; u32 d[4]; } in, out;
    in.v = b;
    #pragma unroll
    for (int i = 0; i < 4; i++) {
        u32 v = in.d[i];
        out.d[i] = ((v >> 16) | (v << 16)) ^ 0x8000u;
    }
    return out.v;
}

// Kaiser-Bessel i0 (A&S), rel err ~5e-7
__device__ __forceinline__ float i0f(float t) {
    if (t < 3.75f) {
        float y = t * t * (1.0f / 14.0625f);
        return 1.0f + y * (3.5156229f + y * (3.0899424f + y * (1.2067492f +
                     y * (0.2659732f + y * (0.0360768f + y * 0.0045813f)))));
    }
    float z = 3.75f / t;
    float p = 0.39894228f + z * (0.01328592f + z * (0.00225319f + z * (-0.00157565f +
              z * (0.00916281f + z * (-0.02057706f + z * (0.02635537f +
              z * (-0.01647633f + z * 0.00392377f)))))));
    return expf(t) * rsqrtf(t) * p;
}

__device__ __forceinline__ float apodf(int i) {
    float x = APOD_C * (float)(i - IMN / 2);
    float arg = sqrtf(BETA2_F - x * x);
    float e = expf(arg);
    float sh = 0.5f * (e - 1.0f / e);
    return arg / sh;
}

// Merged prep: blocks [0,320) build B1 only (B2 derived in the GEMMs);
// blocks [320, 2368) build Abf.
// B1[k][kd] = interleave(M2re, -M2im)
// Abf[c][i1][kd]: apodized complex image, bf16, (re,im) interleaved along kd
__global__ void prep(const float* __restrict__ r, const float* __restrict__ im,
                     u32* __restrict__ B1, u32* __restrict__ A) {
    const int b = blockIdx.x, t = threadIdx.x;
    if (b < (OSN * IMN) / 256) {
        int idx = b * 256 + t;
        int k = idx >> 8, j = idx & 255;
        int p = (k * (j + 32)) % OSN;
        float th = (2.0f * (float)M_PI / (float)OSN) * (float)p;
        float s = ((k + j) & 1) ? -1.0f : 1.0f;
        float sn, cs;
        sincosf(th, &sn, &cs);
        float re = s * cs, imv = -s * sn;
        B1[idx] = f2bf(re) | (f2bf(-imv) << 16);
    } else {
        int idx = (b - (OSN * IMN) / 256) * 256 + t;
        int i2 = idx & 255, i1 = (idx >> 8) & 255;
        float w = apodf(i1) * apodf(i2) * (1.0f / 256.0f);
        A[idx] = f2bf(r[idx] * w) | (f2bf(im[idx] * w) << 16);
    }
}

// GEMM1 (MFMA): Tb[c][k2][kd], kd=2*i1(re),2*i1+1(im).
// R29: NO LDS, 64(M) x 32(N) per-wave tile: 6 loads + 2 derives -> 16 MFMA
// per K-step (MFMA:load 2.7 vs 2.0 at 32x32). Grid (10,4,8)=320 waves.
// Per-output accumulation chain unchanged -> bit-identical.
__launch_bounds__(64)
__global__ void gemm1(const short* __restrict__ Abf, const short* __restrict__ B1,
                      short* __restrict__ Tb) {
    const int c = blockIdx.z;
    const int mBase = blockIdx.y * 64;   // i1
    const int nBase = blockIdx.x * 32;   // k2
    const int t = threadIdx.x;
    const int fm = t & 15, fq = (t >> 4) * 8;
    const short* pa0  = Abf + (long)(c * IMN + mBase + fm) * KD + fq;
    const short* pb10 = B1 + (long)(nBase + fm) * KD + fq;
    const short* pb11 = pb10 + 16 * KD;
    f32x4 zz = {0.f, 0.f, 0.f, 0.f};
    f32x4 accRe[4][2], accIm[4][2];
    #pragma unroll
    for (int i = 0; i < 4; i++)
        #pragma unroll
        for (int j = 0; j < 2; j++) { accRe[i][j] = zz; accIm[i][j] = zz; }

    #pragma unroll
    for (int kc = 0; kc < 16; kc++) {
        const int kb = kc * 32;
        s16x8 a0  = *(const s16x8*)(pa0 + kb);
        s16x8 a1  = *(const s16x8*)(pa0 + 16 * KD + kb);
        s16x8 a2  = *(const s16x8*)(pa0 + 32 * KD + kb);
        s16x8 a3  = *(const s16x8*)(pa0 + 48 * KD + kb);
        s16x8 b10 = *(const s16x8*)(pb10 + kb);
        s16x8 b11 = *(const s16x8*)(pb11 + kb);
        s16x8 b20 = derive_b2(b10);
        s16x8 b21 = derive_b2(b11);
        accRe[0][0] = __builtin_amdgcn_mfma_f32_16x16x32_bf16(a0, b10, accRe[0][0], 0, 0, 0);
        accRe[0][1] = __builtin_amdgcn_mfma_f32_16x16x32_bf16(a0, b11, accRe[0][1], 0, 0, 0);
        accRe[1][0] = __builtin_amdgcn_mfma_f32_16x16x32_bf16(a1, b10, accRe[1][0], 0, 0, 0);
        accRe[1][1] = __builtin_amdgcn_mfma_f32_16x16x32_bf16(a1, b11, accRe[1][1], 0, 0, 0);
        accRe[2][0] = __builtin_amdgcn_mfma_f32_16x16x32_bf16(a2, b10, accRe[2][0], 0, 0, 0);
        accRe[2][1] = __builtin_amdgcn_mfma_f32_16x16x32_bf16(a2, b11, accRe[2][1], 0, 0, 0);
        accRe[3][0] = __builtin_amdgcn_mfma_f32_16x16x32_bf16(a3, b10, accRe[3][0], 0, 0, 0);
        accRe[3][1] = __builtin_amdgcn_mfma_f32_16x16x32_bf16(a3, b11, accRe[3][1], 0, 0, 0);
        accIm[0][0] = __builtin_amdgcn_mfma_f32_16x16x32_bf16(a0, b20, accIm[0][0], 0, 0, 0);
        accIm[0][1] = __builtin_amdgcn_mfma_f32_16x16x32_bf16(a0, b21, accIm[0][1], 0, 0, 0);
        accIm[1][0] = __builtin_amdgcn_mfma_f32_16x16x32_bf16(a1, b20, accIm[1][0], 0, 0, 0);
        accIm[1][1] = __builtin_amdgcn_mfma_f32_16x16x32_bf16(a1, b21, accIm[1][1], 0, 0, 0);
        accIm[2][0] = __builtin_amdgcn_mfma_f32_16x16x32_bf16(a2, b20, accIm[2][0], 0, 0, 0);
        accIm[2][1] = __builtin_amdgcn_mfma_f32_16x16x32_bf16(a2, b21, accIm[2][1], 0, 0, 0);
        accIm[3][0] = __builtin_amdgcn_mfma_f32_16x16x32_bf16(a3, b20, accIm[3][0], 0, 0, 0);
        accIm[3][1] = __builtin_amdgcn_mfma_f32_16x16x32_bf16(a3, b21, accIm[3][1], 0, 0, 0);
    }
    // C/D layout: col = lane&15, row = (lane>>4)*4 + reg
    #pragma unroll
    for (int i = 0; i < 4; i++)
        #pragma unroll
        for (int j = 0; j < 2; j++) {
            int i1b = mBase + i * 16 + (t >> 4) * 4;
            int k2  = nBase + j * 16 + fm;
            s16x8 v;
            #pragma unroll
            for (int r = 0; r < 4; r++) {
                v[2 * r]     = (short)f2bf(accRe[i][j][r]);
                v[2 * r + 1] = (short)f2bf(accIm[i][j][r]);
            }
            *(s16x8*)(Tb + ((long)(c * OSN + k2)) * KD + 2 * i1b) = v;
        }
}

// GEMM2 (MFMA): Gb = padded halo grid [326][328][8] packed bf16.
// R29: NO LDS, 64x32 tile, 6 loads + 4 derives -> 16 MFMA per K-step.
// Grid (10,5,8)=400 waves. Border elements replicated into the halo.
__launch_bounds__(64)
__global__ void gemm2(const short* __restrict__ B1, const short* __restrict__ Tb,
                      u32* __restrict__ Gb) {
    const int c = blockIdx.z;
    const int mBase = blockIdx.y * 64;   // k1
    const int nBase = blockIdx.x * 32;   // k2
    const int t = threadIdx.x;
    const int fm = t & 15, fq = (t >> 4) * 8;
    const short* pa10 = B1 + (long)(mBase + fm) * KD + fq;
    const short* pb0  = Tb + ((long)(c * OSN + nBase + fm)) * KD + fq;
    const short* pb1  = pb0 + 16 * KD;
    f32x4 zz = {0.f, 0.f, 0.f, 0.f};
    f32x4 accRe[4][2], accIm[4][2];
    #pragma unroll
    for (int i = 0; i < 4; i++)
        #pragma unroll
        for (int j = 0; j < 2; j++) { accRe[i][j] = zz; accIm[i][j] = zz; }

    #pragma unroll
    for (int kc = 0; kc < 16; kc++) {
        const int kb = kc * 32;
        s16x8 a10 = *(const s16x8*)(pa10 + kb);
        s16x8 a11 = *(const s16x8*)(pa10 + 16 * KD + kb);
        s16x8 a12 = *(const s16x8*)(pa10 + 32 * KD + kb);
        s16x8 a13 = *(const s16x8*)(pa10 + 48 * KD + kb);
        s16x8 b0  = *(const s16x8*)(pb0 + kb);
        s16x8 b1  = *(const s16x8*)(pb1 + kb);
        s16x8 a20 = derive_b2(a10);
        s16x8 a21 = derive_b2(a11);
        s16x8 a22 = derive_b2(a12);
        s16x8 a23 = derive_b2(a13);
        accRe[0][0] = __builtin_amdgcn_mfma_f32_16x16x32_bf16(a10, b0, accRe[0][0], 0, 0, 0);
        accRe[0][1] = __builtin_amdgcn_mfma_f32_16x16x32_bf16(a10, b1, accRe[0][1], 0, 0, 0);
        accRe[1][0] = __builtin_amdgcn_mfma_f32_16x16x32_bf16(a11, b0, accRe[1][0], 0, 0, 0);
        accRe[1][1] = __builtin_amdgcn_mfma_f32_16x16x32_bf16(a11, b1, accRe[1][1], 0, 0, 0);
        accRe[2][0] = __builtin_amdgcn_mfma_f32_16x16x32_bf16(a12, b0, accRe[2][0], 0, 0, 0);
        accRe[2][1] = __builtin_amdgcn_mfma_f32_16x16x32_bf16(a12, b1, accRe[2][1], 0, 0, 0);
        accRe[3][0] = __builtin_amdgcn_mfma_f32_16x16x32_bf16(a13, b0, accRe[3][0], 0, 0, 0);
        accRe[3][1] = __builtin_amdgcn_mfma_f32_16x16x32_bf16(a13, b1, accRe[3][1], 0, 0, 0);
        accIm[0][0] = __builtin_amdgcn_mfma_f32_16x16x32_bf16(a20, b0, accIm[0][0], 0, 0, 0);
        accIm[0][1] = __builtin_amdgcn_mfma_f32_16x16x32_bf16(a20, b1, accIm[0][1], 0, 0, 0);
        accIm[1][0] = __builtin_amdgcn_mfma_f32_16x16x32_bf16(a21, b0, accIm[1][0], 0, 0, 0);
        accIm[1][1] = __builtin_amdgcn_mfma_f32_16x16x32_bf16(a21, b1, accIm[1][1], 0, 0, 0);
        accIm[2][0] = __builtin_amdgcn_mfma_f32_16x16x32_bf16(a22, b0, accIm[2][0], 0, 0, 0);
        accIm[2][1] = __builtin_amdgcn_mfma_f32_16x16x32_bf16(a22, b1, accIm[2][1], 0, 0, 0);
        accIm[3][0] = __builtin_amdgcn_mfma_f32_16x16x32_bf16(a23, b0, accIm[3][0], 0, 0, 0);
        accIm[3][1] = __builtin_amdgcn_mfma_f32_16x16x32_bf16(a23, b1, accIm[3][1], 0, 0, 0);
    }
    #pragma unroll
    for (int i = 0; i < 4; i++)
        #pragma unroll
        for (int j = 0; j < 2; j++) {
            int k2 = nBase + j * 16 + fm;
            int pc  = k2 + 3;
            int pc2 = (k2 < 3) ? (k2 + 323) : ((k2 >= 317) ? (k2 - 317) : -1);
            #pragma unroll
            for (int r = 0; r < 4; r++) {
                int k1 = mBase + i * 16 + (t >> 4) * 4 + r;
                u32 val = f2bf(accRe[i][j][r]) | (f2bf(accIm[i][j][r]) << 16);
                int pr  = k1 + 3;
                int pr2 = (k1 < 3) ? (k1 + 323) : ((k1 >= 317) ? (k1 - 317) : -1);
                Gb[(long)pr * GPITCH + pc * NCH + c] = val;
                if (pr2 >= 0)              Gb[(long)pr2 * GPITCH + pc  * NCH + c] = val;
                if (pc2 >= 0)              Gb[(long)pr  * GPITCH + pc2 * NCH + c] = val;
                if (pr2 >= 0 && pc2 >= 0)  Gb[(long)pr2 * GPITCH + pc2 * NCH + c] = val;
            }
        }
}

// KB interpolation — padded halo grid, no wrap/modulo. (R27 exact code —
// measured best.) 64 pts/block, 4 lanes/pt x 2 ch (uint2), all 36 loads
// up front (MLP 36), f32x2 packed accumulate, weight evals 3-per-thread
// over 256 threads. LDS result pad [64][9]. Bit-identical accumulation.
__launch_bounds__(256, 4)
__global__ void interp_kernel(const float* __restrict__ trj,
                              const u32* __restrict__ grid,
                              u32* __restrict__ out) {
    const int t = threadIdx.x;
    __shared__ float wxs[64][6], wys[64][6];
    __shared__ int   x0s[64], y0s[64];

    // 768 weight evals / 256 threads = 3 each
    #pragma unroll
    for (int k = 0; k < 3; k++) {
        int e = t + 256 * k;                 // 0..767 = 64 pts x 2 axes x 6 offs
        int ptl = e / 12;
        int rem = e - ptl * 12;
        int axis = rem >= 6 ? 1 : 0;
        int d = rem - axis * 6;
        int pt = blockIdx.x * 64 + ptl;
        float tv = trj[pt * 2 + axis];
        float cc = __fadd_rn(__fmul_rn(tv, 1.25f), 160.0f);
        float v0 = ceilf(__fadd_rn(cc, -3.0f));
        if (d == 0) {
            if (axis) y0s[ptl] = (int)v0; else x0s[ptl] = (int)v0;
        }
        float u = __fdiv_rn(__fsub_rn(v0 + (float)d, cc), 3.0f);
        float wv = i0f(BETA_F * sqrtf(fmaxf(1.0f - u * u, 0.0f)));
        if (axis) wys[ptl][d] = wv; else wxs[ptl][d] = wv;
    }
    __syncthreads();

    const int pl = t >> 2;                 // point 0..63
    const int cp = (t & 3) * 2;            // channel pair base
    const int px = x0s[pl] + 3;            // phys row start, in [0,320]
    const int py = y0s[pl] + 3;            // phys col start, in [0,320]
    const u32* g0 = grid + (long)px * GPITCH + py * NCH + cp;

    // issue all 36 loads before any use (compile-time indices -> registers)
    uint2 g[36];
    #pragma unroll
    for (int dx = 0; dx < 6; dx++)
        #pragma unroll
        for (int dy = 0; dy < 6; dy++)
            g[dx * 6 + dy] = *(const uint2*)(g0 + dx * GPITCH + dy * NCH);

    float wx[6], wy[6];
    #pragma unroll
    for (int d = 0; d < 6; d++) { wx[d] = wxs[pl][d]; wy[d] = wys[pl][d]; }

    f32x2 a0 = {0.f, 0.f}, a1 = {0.f, 0.f};
    #pragma unroll
    for (int dx = 0; dx < 6; dx++) {
        float wxv = wx[dx];
        #pragma unroll
        for (int dy = 0; dy < 6; dy++) {
            uint2 gv = g[dx * 6 + dy];
            float ww = wxv * wy[dy];
            f32x2 w2 = {ww, ww};
            f32x2 v0v = { __uint_as_float(gv.x << 16), __uint_as_float(gv.x & 0xFFFF0000u) };
            f32x2 v1v = { __uint_as_float(gv.y << 16), __uint_as_float(gv.y & 0xFFFF0000u) };
            a0 += v0v * w2;
            a1 += v1v * w2;
        }
    }
    f32x2 sc = {1.0f / 36.0f, 1.0f / 36.0f};
    a0 *= sc; a1 *= sc;

    __shared__ float2 lds[64][9];          // [point][channel], +1 pad
    lds[pl][cp]     = make_float2(a0.x, a0.y);
    lds[pl][cp + 1] = make_float2(a1.x, a1.y);
    __syncthreads();
    // writes: 8 ch x 64 pts = 512 u32; thread writes pts p2 and p2+32 of ch c2
    int c2 = t >> 5, p2 = t & 31;
    float2 va = lds[p2][c2];
    float2 vb = lds[p2 + 32][c2];
    long ob = (long)c2 * NPTS + blockIdx.x * 64;
    out[ob + p2]      = f2bf(va.y) | (f2bf(va.x) << 16);   // (imag, real) pack
    out[ob + p2 + 32] = f2bf(vb.y) | (f2bf(vb.x) << 16);
}

extern "C" void kernel_launch(void* const* d_in, const int* in_sizes, int n_in,
                              void* d_out, int out_size, void* d_ws, size_t ws_size,
                              hipStream_t stream) {
    const float* img_r = (const float*)d_in[0];
    const float* img_i = (const float*)d_in[1];
    const float* trj   = (const float*)d_in[2];

    // d_out (8,388,608 B) scratch (dead before interp overwrites):
    //   Tb @ 0 : 2,621,440 B   B1 @ 2,621,440 : 327,680 B
    //   Abf @ 3,276,800 : 2,097,152 B   (B2 eliminated — derived in-register)
    // d_ws: Gb padded halo grid [326][328][8] u32 = 3,421,696 B.
    char* ob = (char*)d_out;
    short* Tb  = (short*)(ob);
    u32*  B1u  = (u32*)(ob + 2621440);
    u32*  Au   = (u32*)(ob + 3276800);
    u32*  Gb   = (u32*)d_ws;

    prep<<<(OSN * IMN) / 256 + (NCH * IMN * IMN) / 256, 256, 0, stream>>>(
        img_r, img_i, B1u, Au);
    gemm1<<<dim3(OSN / 32, IMN / 64, NCH), 64, 0, stream>>>(
        (const short*)Au, (const short*)B1u, Tb);
    gemm2<<<dim3(OSN / 32, OSN / 64, NCH), 64, 0, stream>>>(
        (const short*)B1u, Tb, Gb);
    interp_kernel<<<NPTS / 64, 256, 0, stream>>>(trj, Gb, (u32*)d_out);
}

// Round 14
// 107.099 us; speedup vs baseline: 1.0500x; 1.0315x over previous
//
#include <hip/hip_runtime.h>
#include <math.h>

// ---- problem constants ----
#define NCH   8
#define IMN   256
#define OSN   320
#define NPTS  (64*4096)            // 262144 trajectory points
#define KD    512                  // doubled K (re,im interleaved)
#define BETA_F   10.9551078f
#define BETA2_F  120.014389f
#define APOD_C   0.05890486225f    // pi*6/320
// padded halo grid: phys row/col = logical + 3; rows 0-2 = logical 317-319,
// rows 323-325 = logical 0-2 (same for cols). Row pitch 328 cols.
#define GROWS 326
#define GCOLS 328
#define GPITCH (GCOLS * NCH)       // u32 per padded grid row = 2624

typedef unsigned short u16;
typedef unsigned int   u32;
typedef __attribute__((ext_vector_type(8))) short s16x8;   // 8 bf16 (4 VGPRs)
typedef __attribute__((ext_vector_type(4))) float f32x4;   // MFMA acc
typedef __attribute__((ext_vector_type(2))) float f32x2;   // packed re,im

__device__ __forceinline__ u32 f2bf(float f) {
    u32 u = __float_as_uint(f);
    return (u + 0x7FFFu + ((u >> 16) & 1u)) >> 16;
}

// B2 = interleave(im, re) derived from B1 = interleave(re, -im):
// per dword: rot16 then flip sign of the (new) low half. Bit-identical to
// a stored table since f2bf(-x) == f2bf(x)^0x8000.
__device__ __forceinline__ s16x8 derive_b2(s16x8 b) {
    union { s16x8 v; u32 d[4]; } in, out;
    in.v = b;
    #pragma unroll
    for (int i = 0; i < 4; i++) {
        u32 v = in.d[i];
        out.d[i] = ((v >> 16) | (v << 16)) ^ 0x8000u;
    }
    return out.v;
}

// Kaiser-Bessel i0 (A&S), rel err ~5e-7
__device__ __forceinline__ float i0f(float t) {
    if (t < 3.75f) {
        float y = t * t * (1.0f / 14.0625f);
        return 1.0f + y * (3.5156229f + y * (3.0899424f + y * (1.2067492f +
                     y * (0.2659732f + y * (0.0360768f + y * 0.0045813f)))));
    }
    float z = 3.75f / t;
    float p = 0.39894228f + z * (0.01328592f + z * (0.00225319f + z * (-0.00157565f +
              z * (0.00916281f + z * (-0.02057706f + z * (0.02635537f +
              z * (-0.01647633f + z * 0.00392377f)))))));
    return expf(t) * rsqrtf(t) * p;
}

__device__ __forceinline__ float apodf(int i) {
    float x = APOD_C * (float)(i - IMN / 2);
    float arg = sqrtf(BETA2_F - x * x);
    float e = expf(arg);
    float sh = 0.5f * (e - 1.0f / e);
    return arg / sh;
}

// Merged prep: blocks [0,320) build B1 only (B2 derived in the GEMMs);
// blocks [320, 2368) build Abf.
// B1[k][kd] = interleave(M2re, -M2im)
// Abf[c][i1][kd]: apodized complex image, bf16, (re,im) interleaved along kd
__global__ void prep(const float* __restrict__ r, const float* __restrict__ im,
                     u32* __restrict__ B1, u32* __restrict__ A) {
    const int b = blockIdx.x, t = threadIdx.x;
    if (b < (OSN * IMN) / 256) {
        int idx = b * 256 + t;
        int k = idx >> 8, j = idx & 255;
        int p = (k * (j + 32)) % OSN;
        float th = (2.0f * (float)M_PI / (float)OSN) * (float)p;
        float s = ((k + j) & 1) ? -1.0f : 1.0f;
        float sn, cs;
        sincosf(th, &sn, &cs);
        float re = s * cs, imv = -s * sn;
        B1[idx] = f2bf(re) | (f2bf(-imv) << 16);
    } else {
        int idx = (b - (OSN * IMN) / 256) * 256 + t;
        int i2 = idx & 255, i1 = (idx >> 8) & 255;
        float w = apodf(i1) * apodf(i2) * (1.0f / 256.0f);
        A[idx] = f2bf(r[idx] * w) | (f2bf(im[idx] * w) << 16);
    }
}

// GEMM1 (MFMA): Tb[c][k2][kd], kd=2*i1(re),2*i1+1(im).
// R24/R27 config (measured best): NO LDS, 32x32 per-wave tile, 4 loads +
// 2 derives + 8 MFMA per K-step, zero barriers. Grid (10,8,8)=640 waves.
__launch_bounds__(64)
__global__ void gemm1(const short* __restrict__ Abf, const short* __restrict__ B1,
                      short* __restrict__ Tb) {
    const int c = blockIdx.z;
    const int mBase = blockIdx.y * 32;   // i1
    const int nBase = blockIdx.x * 32;   // k2
    const int t = threadIdx.x;
    const int fm = t & 15, fq = (t >> 4) * 8;
    const short* pa0  = Abf + (long)(c * IMN + mBase + fm) * KD + fq;
    const short* pa1  = pa0 + 16 * KD;
    const short* pb10 = B1 + (long)(nBase + fm) * KD + fq;
    const short* pb11 = pb10 + 16 * KD;
    f32x4 zz = {0.f, 0.f, 0.f, 0.f};
    f32x4 accRe[2][2], accIm[2][2];
    #pragma unroll
    for (int i = 0; i < 2; i++)
        #pragma unroll
        for (int j = 0; j < 2; j++) { accRe[i][j] = zz; accIm[i][j] = zz; }

    #pragma unroll
    for (int kc = 0; kc < 16; kc++) {
        const int kb = kc * 32;
        s16x8 a0  = *(const s16x8*)(pa0  + kb);
        s16x8 a1  = *(const s16x8*)(pa1  + kb);
        s16x8 b10 = *(const s16x8*)(pb10 + kb);
        s16x8 b11 = *(const s16x8*)(pb11 + kb);
        s16x8 b20 = derive_b2(b10);
        s16x8 b21 = derive_b2(b11);
        accRe[0][0] = __builtin_amdgcn_mfma_f32_16x16x32_bf16(a0, b10, accRe[0][0], 0, 0, 0);
        accRe[0][1] = __builtin_amdgcn_mfma_f32_16x16x32_bf16(a0, b11, accRe[0][1], 0, 0, 0);
        accRe[1][0] = __builtin_amdgcn_mfma_f32_16x16x32_bf16(a1, b10, accRe[1][0], 0, 0, 0);
        accRe[1][1] = __builtin_amdgcn_mfma_f32_16x16x32_bf16(a1, b11, accRe[1][1], 0, 0, 0);
        accIm[0][0] = __builtin_amdgcn_mfma_f32_16x16x32_bf16(a0, b20, accIm[0][0], 0, 0, 0);
        accIm[0][1] = __builtin_amdgcn_mfma_f32_16x16x32_bf16(a0, b21, accIm[0][1], 0, 0, 0);
        accIm[1][0] = __builtin_amdgcn_mfma_f32_16x16x32_bf16(a1, b20, accIm[1][0], 0, 0, 0);
        accIm[1][1] = __builtin_amdgcn_mfma_f32_16x16x32_bf16(a1, b21, accIm[1][1], 0, 0, 0);
    }
    // C/D layout: col = lane&15, row = (lane>>4)*4 + reg
    #pragma unroll
    for (int i = 0; i < 2; i++)
        #pragma unroll
        for (int j = 0; j < 2; j++) {
            int i1b = mBase + i * 16 + (t >> 4) * 4;
            int k2  = nBase + j * 16 + fm;
            s16x8 v;
            #pragma unroll
            for (int r = 0; r < 4; r++) {
                v[2 * r]     = (short)f2bf(accRe[i][j][r]);
                v[2 * r + 1] = (short)f2bf(accIm[i][j][r]);
            }
            *(s16x8*)(Tb + ((long)(c * OSN + k2)) * KD + 2 * i1b) = v;
        }
}

// GEMM2 (MFMA): Gb = padded halo grid [326][328][8] packed bf16.
// R24/R27 config: NO LDS, 32x32 tile, 4 loads/K-step (a2 derived from a1).
// Border elements replicated into the halo (up to 4 stores).
__launch_bounds__(64)
__global__ void gemm2(const short* __restrict__ B1, const short* __restrict__ Tb,
                      u32* __restrict__ Gb) {
    const int c = blockIdx.z;
    const int mBase = blockIdx.y * 32;   // k1
    const int nBase = blockIdx.x * 32;   // k2
    const int t = threadIdx.x;
    const int fm = t & 15, fq = (t >> 4) * 8;
    const short* pa10 = B1 + (long)(mBase + fm) * KD + fq;
    const short* pa11 = pa10 + 16 * KD;
    const short* pb0  = Tb + ((long)(c * OSN + nBase + fm)) * KD + fq;
    const short* pb1  = pb0 + 16 * KD;
    f32x4 zz = {0.f, 0.f, 0.f, 0.f};
    f32x4 accRe[2][2], accIm[2][2];
    #pragma unroll
    for (int i = 0; i < 2; i++)
        #pragma unroll
        for (int j = 0; j < 2; j++) { accRe[i][j] = zz; accIm[i][j] = zz; }

    #pragma unroll
    for (int kc = 0; kc < 16; kc++) {
        const int kb = kc * 32;
        s16x8 a10 = *(const s16x8*)(pa10 + kb);
        s16x8 a11 = *(const s16x8*)(pa11 + kb);
        s16x8 b0  = *(const s16x8*)(pb0  + kb);
        s16x8 b1  = *(const s16x8*)(pb1  + kb);
        s16x8 a20 = derive_b2(a10);
        s16x8 a21 = derive_b2(a11);
        accRe[0][0] = __builtin_amdgcn_mfma_f32_16x16x32_bf16(a10, b0, accRe[0][0], 0, 0, 0);
        accRe[0][1] = __builtin_amdgcn_mfma_f32_16x16x32_bf16(a10, b1, accRe[0][1], 0, 0, 0);
        accRe[1][0] = __builtin_amdgcn_mfma_f32_16x16x32_bf16(a11, b0, accRe[1][0], 0, 0, 0);
        accRe[1][1] = __builtin_amdgcn_mfma_f32_16x16x32_bf16(a11, b1, accRe[1][1], 0, 0, 0);
        accIm[0][0] = __builtin_amdgcn_mfma_f32_16x16x32_bf16(a20, b0, accIm[0][0], 0, 0, 0);
        accIm[0][1] = __builtin_amdgcn_mfma_f32_16x16x32_bf16(a20, b1, accIm[0][1], 0, 0, 0);
        accIm[1][0] = __builtin_amdgcn_mfma_f32_16x16x32_bf16(a21, b0, accIm[1][0], 0, 0, 0);
        accIm[1][1] = __builtin_amdgcn_mfma_f32_16x16x32_bf16(a21, b1, accIm[1][1], 0, 0, 0);
    }
    #pragma unroll
    for (int i = 0; i < 2; i++)
        #pragma unroll
        for (int j = 0; j < 2; j++) {
            int k2 = nBase + j * 16 + fm;
            int pc  = k2 + 3;
            int pc2 = (k2 < 3) ? (k2 + 323) : ((k2 >= 317) ? (k2 - 317) : -1);
            #pragma unroll
            for (int r = 0; r < 4; r++) {
                int k1 = mBase + i * 16 + (t >> 4) * 4 + r;
                u32 val = f2bf(accRe[i][j][r]) | (f2bf(accIm[i][j][r]) << 16);
                int pr  = k1 + 3;
                int pr2 = (k1 < 3) ? (k1 + 323) : ((k1 >= 317) ? (k1 - 317) : -1);
                Gb[(long)pr * GPITCH + pc * NCH + c] = val;
                if (pr2 >= 0)              Gb[(long)pr2 * GPITCH + pc  * NCH + c] = val;
                if (pc2 >= 0)              Gb[(long)pr  * GPITCH + pc2 * NCH + c] = val;
                if (pr2 >= 0 && pc2 >= 0)  Gb[(long)pr2 * GPITCH + pc2 * NCH + c] = val;
            }
        }
}

// KB interpolation — padded halo grid, no wrap/modulo. (R27 exact code —
// measured best.) 64 pts/block, 4 lanes/pt x 2 ch (uint2), all 36 loads
// up front (MLP 36), f32x2 packed accumulate, weight evals 3-per-thread
// over 256 threads. LDS result pad [64][9]. Bit-identical accumulation.
__launch_bounds__(256, 4)
__global__ void interp_kernel(const float* __restrict__ trj,
                              const u32* __restrict__ grid,
                              u32* __restrict__ out) {
    const int t = threadIdx.x;
    __shared__ float wxs[64][6], wys[64][6];
    __shared__ int   x0s[64], y0s[64];

    // 768 weight evals / 256 threads = 3 each
    #pragma unroll
    for (int k = 0; k < 3; k++) {
        int e = t + 256 * k;                 // 0..767 = 64 pts x 2 axes x 6 offs
        int ptl = e / 12;
        int rem = e - ptl * 12;
        int axis = rem >= 6 ? 1 : 0;
        int d = rem - axis * 6;
        int pt = blockIdx.x * 64 + ptl;
        float tv = trj[pt * 2 + axis];
        float cc = __fadd_rn(__fmul_rn(tv, 1.25f), 160.0f);
        float v0 = ceilf(__fadd_rn(cc, -3.0f));
        if (d == 0) {
            if (axis) y0s[ptl] = (int)v0; else x0s[ptl] = (int)v0;
        }
        float u = __fdiv_rn(__fsub_rn(v0 + (float)d, cc), 3.0f);
        float wv = i0f(BETA_F * sqrtf(fmaxf(1.0f - u * u, 0.0f)));
        if (axis) wys[ptl][d] = wv; else wxs[ptl][d] = wv;
    }
    __syncthreads();

    const int pl = t >> 2;                 // point 0..63
    const int cp = (t & 3) * 2;            // channel pair base
    const int px = x0s[pl] + 3;            // phys row start, in [0,320]
    const int py = y0s[pl] + 3;            // phys col start, in [0,320]
    const u32* g0 = grid + (long)px * GPITCH + py * NCH + cp;

    // issue all 36 loads before any use (compile-time indices -> registers)
    uint2 g[36];
    #pragma unroll
    for (int dx = 0; dx < 6; dx++)
        #pragma unroll
        for (int dy = 0; dy < 6; dy++)
            g[dx * 6 + dy] = *(const uint2*)(g0 + dx * GPITCH + dy * NCH);

    float wx[6], wy[6];
    #pragma unroll
    for (int d = 0; d < 6; d++) { wx[d] = wxs[pl][d]; wy[d] = wys[pl][d]; }

    f32x2 a0 = {0.f, 0.f}, a1 = {0.f, 0.f};
    #pragma unroll
    for (int dx = 0; dx < 6; dx++) {
        float wxv = wx[dx];
        #pragma unroll
        for (int dy = 0; dy < 6; dy++) {
            uint2 gv = g[dx * 6 + dy];
            float ww = wxv * wy[dy];
            f32x2 w2 = {ww, ww};
            f32x2 v0v = { __uint_as_float(gv.x << 16), __uint_as_float(gv.x & 0xFFFF0000u) };
            f32x2 v1v = { __uint_as_float(gv.y << 16), __uint_as_float(gv.y & 0xFFFF0000u) };
            a0 += v0v * w2;
            a1 += v1v * w2;
        }
    }
    f32x2 sc = {1.0f / 36.0f, 1.0f / 36.0f};
    a0 *= sc; a1 *= sc;

    __shared__ float2 lds[64][9];          // [point][channel], +1 pad
    lds[pl][cp]     = make_float2(a0.x, a0.y);
    lds[pl][cp + 1] = make_float2(a1.x, a1.y);
    __syncthreads();
    // writes: 8 ch x 64 pts = 512 u32; thread writes pts p2 and p2+32 of ch c2
    int c2 = t >> 5, p2 = t & 31;
    float2 va = lds[p2][c2];
    float2 vb = lds[p2 + 32][c2];
    long ob = (long)c2 * NPTS + blockIdx.x * 64;
    out[ob + p2]      = f2bf(va.y) | (f2bf(va.x) << 16);   // (imag, real) pack
    out[ob + p2 + 32] = f2bf(vb.y) | (f2bf(vb.x) << 16);
}

extern "C" void kernel_launch(void* const* d_in, const int* in_sizes, int n_in,
                              void* d_out, int out_size, void* d_ws, size_t ws_size,
                              hipStream_t stream) {
    const float* img_r = (const float*)d_in[0];
    const float* img_i = (const float*)d_in[1];
    const float* trj   = (const float*)d_in[2];

    // d_out (8,388,608 B) scratch (dead before interp overwrites):
    //   Tb @ 0 : 2,621,440 B   B1 @ 2,621,440 : 327,680 B
    //   Abf @ 3,276,800 : 2,097,152 B   (B2 eliminated — derived in-register)
    // d_ws: Gb padded halo grid [326][328][8] u32 = 3,421,696 B.
    char* ob = (char*)d_out;
    short* Tb  = (short*)(ob);
    u32*  B1u  = (u32*)(ob + 2621440);
    u32*  Au   = (u32*)(ob + 3276800);
    u32*  Gb   = (u32*)d_ws;

    prep<<<(OSN * IMN) / 256 + (NCH * IMN * IMN) / 256, 256, 0, stream>>>(
        img_r, img_i, B1u, Au);
    gemm1<<<dim3(OSN / 32, IMN / 32, NCH), 64, 0, stream>>>(
        (const short*)Au, (const short*)B1u, Tb);
    gemm2<<<dim3(OSN / 32, OSN / 32, NCH), 64, 0, stream>>>(
        (const short*)B1u, Tb, Gb);
    interp_kernel<<<NPTS / 64, 256, 0, stream>>>(trj, Gb, (u32*)d_out);
}